// Round 1
// 3624.275 us; speedup vs baseline: 1.0307x; 1.0307x over previous
//
#include <hip/hip_runtime.h>
#include <math.h>

#define T_LEN 512
#define BATCH 128
#define HID   256
#define BH    (BATCH*HID)   // 32768

// ---------------- helpers ----------------
__device__ __forceinline__ float sigmoid_f(float v) {
    return 1.f / (1.f + __expf(-v));
}
__device__ __forceinline__ float tanh_f(float v) {
    v = fminf(fmaxf(v, -15.f), 15.f);
    float e = __expf(2.f * v);
    return (e - 1.f) / (e + 1.f);
}
__device__ __forceinline__ float4 ldf4(const float* p) {
    return *reinterpret_cast<const float4*>(p);
}
__device__ __forceinline__ void fma4(float4& a, const float4 v, const float4 w) {
    a.x = fmaf(v.x, w.x, a.x);
    a.y = fmaf(v.y, w.y, a.y);
    a.z = fmaf(v.z, w.z, a.z);
    a.w = fmaf(v.w, w.w, a.w);
}
__device__ __forceinline__ float hsum4(const float4 a) {
    return (a.x + a.y) + (a.z + a.w);
}
// Pin a value into a VGPR so invariant weight loads can't be sunk into the loop.
__device__ __forceinline__ void pin4(float4& v) {
    asm volatile("" : "+v"(v.x), "+v"(v.y), "+v"(v.z), "+v"(v.w));
}
// agent-scope relaxed atomics: coherent across XCDs, no cache flushes
__device__ __forceinline__ void astore(float* p, float v) {
    __hip_atomic_store(p, v, __ATOMIC_RELAXED, __HIP_MEMORY_SCOPE_AGENT);
}
__device__ __forceinline__ float2 af2(const float* p) {
    unsigned long long u = __hip_atomic_load((const unsigned long long*)p,
                                             __ATOMIC_RELAXED, __HIP_MEMORY_SCOPE_AGENT);
    union { unsigned long long u; float2 f; } c; c.u = u;
    return c.f;
}
__device__ __forceinline__ float4 af4(const float* p) {
    const float2 a = af2(p), b = af2(p + 2);
    return make_float4(a.x, a.y, b.x, b.y);
}
// DPP row_shr prefix reduction within 16-lane groups; lane (kc==15) gets the sum.
template<int CTRL>
__device__ __forceinline__ float dpp_mv(float x) {
    return __int_as_float(__builtin_amdgcn_update_dpp(
        0, __float_as_int(x), CTRL, 0xF, 0xF, true));
}
__device__ __forceinline__ float red16(float x) {
    x += dpp_mv<0x111>(x);  // row_shr:1
    x += dpp_mv<0x112>(x);  // row_shr:2
    x += dpp_mv<0x114>(x);  // row_shr:4
    x += dpp_mv<0x118>(x);  // row_shr:8
    return x;               // valid in lane kc==15 of each 16-group
}

// ---------------- persistent LSTM, split-critical-path schedule ----------------
// grid 512 x 256, 2 blocks/CU. bid: bg = bid&15 (8 batch rows), layer=(bid>>4)&1,
// jt = bid>>5 (16 j each). tid: jp = tid>>4 (one j), kc = tid&15 (K-chunk of 16).
//
// SCHEDULE (the point of this version): the K=512 GEMV is only half critical.
//  - recurrent half (W_hh·h[t-1], K=256): distance-1 dependency -> critical path.
//  - input half (W_ih·x[t] for L0 [static input!], W_ih·h0[t] for L1): has >=1
//    iteration of slack once L1 lags an extra step.
// L0 computes h0[s-1] at iteration s (lag 1); L1 computes h1[s-3] (lag 3).
// Per iteration: poll -> stage -> critical K=256 GEMV (+ ls_ax from last iter
// + bias) -> epilogue -> publish flag -> THEN input-half GEMV for the NEXT step
// into ls_ax. The input-half work now executes inside the publish->poll latency
// window that previously showed up as 58% VALU-idle.
//
// Flags: flag = s+1 published at end of iter s. Pollers at iter s need:
//   own layer >= s; other layer >= s (L1 needs h0[s-2]); EXCEPT L0 only needs
//   L1 >= s-1 (buffer-reuse gating only). Triple-buffered h: every slot
//   overwrite is >= 2 iterations behind its last flag-gated reader (checked
//   per slot: L0 writes h0[s-1] over h0[s-4], readers at iters s-2 <= gate).
__global__ __launch_bounds__(256)
__attribute__((amdgpu_waves_per_eu(2, 2)))
void lstm_persist(
    const float* __restrict__ x,
    const float* __restrict__ Wih, const float* __restrict__ Whh,
    const float* __restrict__ bih, const float* __restrict__ bhh,
    float* __restrict__ out,
    float* __restrict__ h0buf,   // 3 * BH (triple-buffered by timestep%3)
    float* __restrict__ h1buf,   // 3 * BH
    int* __restrict__ flags)     // 16 groups x 32 blocks
{
    __shared__ float ls_in[8 * 576];   // 8 b x 16 chunks x 36 (pad -> 2-way alias = free)
    __shared__ float ls_a [128 * 4];   // critical-half sums (+bias+ax) [b*16+jp][g]
    __shared__ float ls_ax[128 * 4];   // input-half sums for NEXT step [b*16+jp][g]
    __shared__ float ls_c [128];       // c[b*16+jp]

    const int tid = threadIdx.x;
    const int bid = blockIdx.x;
    const int bg = bid & 15;
    const int layer = (bid >> 4) & 1;
    const int jt = bid >> 5;
    const int jp = tid >> 4;
    const int kc = tid & 15;
    const int j = jt * 16 + jp;
    const int Bg0 = bg * 8;

    const float* Wih_l = Wih + (size_t)layer * 4 * HID * HID;
    const float* Whh_l = Whh + (size_t)layer * 4 * HID * HID;
    const float* bih_l = bih + layer * 4 * HID;
    const float* bhh_l = bhh + layer * 4 * HID;

    // 4 gate rows x 16 K-cols per half = 128 VGPRs total, loaded once, pinned.
    float4 wih[4][4], whh[4][4];
    float bias[4];
    #pragma unroll
    for (int g = 0; g < 4; ++g) {
        const int row = g * HID + j;             // row in 4H
        const float* pih = Wih_l + (size_t)row * HID + kc * 16;
        const float* phh = Whh_l + (size_t)row * HID + kc * 16;
        #pragma unroll
        for (int m = 0; m < 4; ++m) {
            wih[g][m] = ldf4(pih + m * 4);
            pin4(wih[g][m]);
            whh[g][m] = ldf4(phh + m * 4);
            pin4(whh[g][m]);
        }
        bias[g] = bih_l[row] + bhh_l[row];
        asm volatile("" : "+v"(bias[g]));
    }

    if (tid < 128) ls_c[tid] = 0.f;   // synced by first barrier below

    int* myflag = flags + bg * 32 + layer * 16 + jt;

    #pragma unroll 1
    for (int s = 0; s <= T_LEN + 2; ++s) {
        if (s > 0 && tid < 32) {
            // signed compare: 0xAAAAAAAA poison is negative -> blocks until real store
            const int thr = (layer == 0 && tid >= 16) ? (s - 1) : s;
            const int* f = flags + bg * 32 + tid;
            while (__hip_atomic_load(f, __ATOMIC_RELAXED, __HIP_MEMORY_SCOPE_AGENT) < thr)
                __builtin_amdgcn_s_sleep(1);
        }
        __syncthreads();   // everyone past poll; inputs published & visible

        // crit: compute h[t] (t = s-1 for L0, s-3 for L1) from recurrent half.
        // xact: compute input-half partial sums for the step after t.
        const bool crit = (layer == 0) ? (s >= 1 && s <= T_LEN) : (s >= 3);
        const bool xact = (layer == 0) ? (s < T_LEN) : (s >= 2 && s <= T_LEN + 1);
        const bool zeroh = (layer == 0) ? (s == 1) : (s == 3);   // h[t-1] = 0

        if (crit || xact) {
            // ls_in layout: [b][cols 0..255 = input half | 256..511 = recurrent half]
            const float* ph0 = h0buf + (size_t)((s + 1) % 3) * BH;  // h0[s-2]
            const float* ph1 = h1buf + (size_t)((s + 2) % 3) * BH;  // h1[s-4]
            #pragma unroll
            for (int i = 0; i < 4; ++i) {
                const int F = tid + 256 * i;     // f4 index in 8x128
                const int b = F >> 7;
                const int rr = F & 127;
                const int col = (rr & 63) * 4;
                const size_t row = (size_t)(Bg0 + b) * HID + col;
                float4 v = make_float4(0.f, 0.f, 0.f, 0.f);
                if ((rr >> 6) == 0) {            // input half (slack)
                    if (xact)
                        v = (layer == 0) ? ldf4(x + (size_t)s * BH + row)
                                         : af4(ph0 + row);
                } else if (crit && !zeroh) {     // recurrent half (critical)
                    v = (layer == 0) ? af4(ph0 + row) : af4(ph1 + row);
                }
                *(float4*)(ls_in + b * 576 + (rr >> 3) * 36 + (rr & 7) * 4) = v;
            }
        }
        __syncthreads();   // staging visible

        if (crit) {
            // ---- CRITICAL: recurrent K=256 GEMV; each thread 16 K, reduce over 16 lanes
            #pragma unroll 2
            for (int b = 0; b < 8; ++b) {
                const float4* Lp = (const float4*)(ls_in + b * 576 + 288
                                                   + (kc >> 1) * 36 + (kc & 1) * 16);
                float4 in[4];
                #pragma unroll
                for (int m = 0; m < 4; ++m) in[m] = Lp[m];
                float4 ac[4];
                #pragma unroll
                for (int g = 0; g < 4; ++g) ac[g] = make_float4(0.f, 0.f, 0.f, 0.f);
                #pragma unroll
                for (int m = 0; m < 4; ++m) {
                    #pragma unroll
                    for (int g = 0; g < 4; ++g) fma4(ac[g], in[m], whh[g][m]);
                }
                const float a0 = red16(hsum4(ac[0]));
                const float a1 = red16(hsum4(ac[1]));
                const float a2 = red16(hsum4(ac[2]));
                const float a3 = red16(hsum4(ac[3]));
                if (kc == 15) {   // owner: combine with input-half sums from last iter
                    const int cell = b * 16 + jp;
                    const float* axp = ls_ax + cell * 4;
                    float* ap = ls_a + cell * 4;
                    ap[0] = a0 + bias[0] + axp[0];
                    ap[1] = a1 + bias[1] + axp[1];
                    ap[2] = a2 + bias[2] + axp[2];
                    ap[3] = a3 + bias[3] + axp[3];
                }
            }
        }
        __syncthreads();   // ls_a complete

        if (crit && tid < 128) {
            // ---- all-lane epilogue: thread = one (b, j) cell ----
            const int bb = tid >> 4;
            const int jpp = tid & 15;
            const int t = (layer == 0) ? (s - 1) : (s - 3);
            float* hst = (layer == 0) ? (h0buf + (size_t)((s + 2) % 3) * BH)   // h0[s-1]
                                      : (h1buf + (size_t)(s % 3) * BH);        // h1[s-3]
            const bool last = (t == T_LEN - 1);
            const float* ap = ls_a + tid * 4;
            const float gi = sigmoid_f(ap[0]);
            const float gf = sigmoid_f(ap[1]);
            const float gg = tanh_f   (ap[2]);
            const float go = sigmoid_f(ap[3]);
            const float cold = ls_c[tid];
            const float cnew = fmaf(gf, cold, gi * gg);
            ls_c[tid] = cnew;
            const float h = go * tanh_f(cnew);
            const int B = Bg0 + bb;
            const int jg = jt * 16 + jpp;
            astore(hst + (size_t)B * HID + jg, h);
            if (layer == 1)
                out[(size_t)t * BH + (size_t)B * HID + jg] = h;
            if (last) {
                float* hn  = out + (size_t)T_LEN * BH;
                float* cnp = hn + 2 * BH;
                hn [(size_t)layer * BH + (size_t)B * HID + jg] = h;
                cnp[(size_t)layer * BH + (size_t)B * HID + jg] = cnew;
            }
        }
        __syncthreads();   // h-stores drained (vmcnt(0) before s_barrier)
        if (s <= T_LEN + 1 && tid == 0)
            __hip_atomic_store(myflag, s + 1, __ATOMIC_RELAXED, __HIP_MEMORY_SCOPE_AGENT);

        if (xact) {
            // ---- SLACK: input-half K=256 GEMV for the NEXT step, runs inside the
            // publish->poll window. Results to ls_ax, consumed next iteration.
            #pragma unroll 2
            for (int b = 0; b < 8; ++b) {
                const float4* Lp = (const float4*)(ls_in + b * 576
                                                   + (kc >> 1) * 36 + (kc & 1) * 16);
                float4 in[4];
                #pragma unroll
                for (int m = 0; m < 4; ++m) in[m] = Lp[m];
                float4 ac[4];
                #pragma unroll
                for (int g = 0; g < 4; ++g) ac[g] = make_float4(0.f, 0.f, 0.f, 0.f);
                #pragma unroll
                for (int m = 0; m < 4; ++m) {
                    #pragma unroll
                    for (int g = 0; g < 4; ++g) fma4(ac[g], in[m], wih[g][m]);
                }
                const float a0 = red16(hsum4(ac[0]));
                const float a1 = red16(hsum4(ac[1]));
                const float a2 = red16(hsum4(ac[2]));
                const float a3 = red16(hsum4(ac[3]));
                if (kc == 15) {
                    float* axp = ls_ax + (b * 16 + jp) * 4;
                    axp[0] = a0;
                    axp[1] = a1;
                    axp[2] = a2;
                    axp[3] = a3;
                }
            }
        }
    }
}

extern "C" void kernel_launch(void* const* d_in, const int* in_sizes, int n_in,
                              void* d_out, int out_size, void* d_ws, size_t ws_size,
                              hipStream_t stream) {
    const float* x   = (const float*)d_in[0];
    const float* Wih = (const float*)d_in[1];
    const float* Whh = (const float*)d_in[2];
    const float* bih = (const float*)d_in[3];
    const float* bhh = (const float*)d_in[4];
    float* out = (float*)d_out;

    float* h0 = (float*)d_ws;          // 3*BH
    float* h1 = h0 + 3 * BH;           // 3*BH
    int* flags = (int*)(h1 + 3 * BH);  // 512 ints, poison-proof (signed compare)

    hipLaunchKernelGGL(lstm_persist, dim3(512), dim3(256), 0, stream,
                       x, Wih, Whh, bih, bhh, out, h0, h1, flags);
}